// Round 9
// baseline (290.545 us; speedup 1.0000x reference)
//
#include <hip/hip_runtime.h>
#include <math.h>

#define NN 96
#define DD 512
#define PP 9120          // NN*(NN-1)
#define EPSF 1e-8f
#define INV_TEMP 100.0f
#define LOG2E 1.4426950408889634f
#define RT 16            // tasks per lse block (2x amortization of per-wave overhead)
#define NTASK (2*PP)     // 18240
#define NBLK_T (NTASK/RT) // 1140
#define CBASE (PP/RT)    // 570: first block index handling column tasks
#define NPBLK 1152       // prep blocks (8 pairs each = 9216)

// ws float-offset layout (no init-dependent state: poison-proof)
#define OFF_G     0        // G  = txt*img^T   [96*96]
#define OFF_GT    9216     // GT = G^T
#define OFF_WT    18432    // wt[k][l] = 1/(||t_k-t_l||+eps), diag 0
#define OFF_WM    27648
#define OFF_WST   36864    // wt * log2e
#define OFF_WSM   46080    // wm * log2e
#define OFF_WMAXS 55296    // [0..1151] per-prep-block max wt, [1152..2303] max wm
#define OFF_BSUM  57600    // [0..1139] per-lse-block partial sums

__device__ __forceinline__ void decomp(unsigned p, int& i, int& j) {
    unsigned ii = p / 95u;
    unsigned r  = p - ii * 95u;
    i = (int)ii;
    j = (int)(r + (r >= ii ? 1u : 0u));
}

// K1: pair-per-wave prep (proven R4+). 1152 blocks x 4 waves x 2 pairs.
__global__ __launch_bounds__(256) void prep_kernel(const float* __restrict__ txt,
                                                   const float* __restrict__ img,
                                                   float* __restrict__ ws) {
    __shared__ float wtw[4], wmw[4];
    int b = blockIdx.x, tid = threadIdx.x;
    int lane = tid & 63, wv = tid >> 6;
    const float4* T4 = (const float4*)txt;   // row stride 128 float4
    const float4* M4 = (const float4*)img;
    float bwt = 0.f, bwm = 0.f;

    #pragma unroll
    for (int q = 0; q < 2; ++q) {
        int pp = b * 8 + wv * 2 + q;         // 0..9215
        int i = pp / NN, j = pp - i * NN;
        const float4* Ti = T4 + i * 128 + 2 * lane;
        const float4* Tj = T4 + j * 128 + 2 * lane;
        const float4* Mi = M4 + i * 128 + 2 * lane;
        const float4* Mj = M4 + j * 128 + 2 * lane;
        float gij = 0.f, nt2 = 0.f, nm2 = 0.f;
        #pragma unroll
        for (int u = 0; u < 2; ++u) {
            float4 a = Ti[u], t = Tj[u], c = Mi[u], d = Mj[u];
            gij += a.x*d.x + a.y*d.y + a.z*d.z + a.w*d.w;       // <t_i, m_j>
            float d0 = a.x-t.x, d1 = a.y-t.y, d2 = a.z-t.z, d3 = a.w-t.w;
            nt2 += d0*d0 + d1*d1 + d2*d2 + d3*d3;               // ||t_i-t_j||^2
            float e0 = c.x-d.x, e1 = c.y-d.y, e2 = c.z-d.z, e3 = c.w-d.w;
            nm2 += e0*e0 + e1*e1 + e2*e2 + e3*e3;               // ||m_i-m_j||^2
        }
        #pragma unroll
        for (int off = 32; off > 0; off >>= 1) {
            gij += __shfl_xor(gij, off, 64);
            nt2 += __shfl_xor(nt2, off, 64);
            nm2 += __shfl_xor(nm2, off, 64);
        }
        float wt = 0.f, wm = 0.f;
        if (i != j) {
            wt = 1.f / (sqrtf(fmaxf(nt2, 0.f)) + EPSF);
            wm = 1.f / (sqrtf(fmaxf(nm2, 0.f)) + EPSF);
        }
        bwt = fmaxf(bwt, wt); bwm = fmaxf(bwm, wm);
        if (lane == 0) {
            int t0 = i * NN + j;
            ws[OFF_G  + t0] = gij;
            ws[OFF_GT + j * NN + i] = gij;   // mirror pair fills GT[i*NN+j]
            ws[OFF_WT  + t0] = wt;
            ws[OFF_WM  + t0] = wm;
            ws[OFF_WST + t0] = wt * LOG2E;
            ws[OFF_WSM + t0] = wm * LOG2E;
        }
    }
    if (lane == 0) { wtw[wv] = bwt; wmw[wv] = bwm; }
    __syncthreads();
    if (tid == 0) {
        ws[OFF_WMAXS + b]         = fmaxf(fmaxf(wtw[0], wtw[1]), fmaxf(wtw[2], wtw[3]));
        ws[OFF_WMAXS + NPBLK + b] = fmaxf(fmaxf(wmw[0], wmw[1]), fmaxf(wmw[2], wmw[3]));
    }
}

// K2: lse, RT=16 tasks per block (1140 blocks). LDS-broadcast sweep engine
// (lowest VGPR), w one-ahead prefetch, BSUM partial store (no atomics).
__global__ __launch_bounds__(256, 4) void lse_kernel(const float* __restrict__ ws,
                                                     float* __restrict__ wsw) {
    __shared__ float A[RT * NN];     // 16 x 96 = 6 KB
    __shared__ float M2s[RT];        // M * log2e
    __shared__ float Ms[RT];         // M
    __shared__ float wred[4][RT];
    __shared__ float cred[RT];

    int tid = threadIdx.x, lane = tid & 63, wv = tid >> 6;
    int b = blockIdx.x;
    bool is_col = (b >= CBASE);
    const float* Mat    = ws + (is_col ? OFF_GT  : OFF_G);
    const float* wself  = ws + (is_col ? OFF_WM  : OFF_WT);
    const float* wsweep = ws + (is_col ? OFF_WST : OFF_WSM);

    // Wmax: rows sweep wm (partials at NPBLK..), cols sweep wt (partials at 0..)
    const float* wmx = ws + OFF_WMAXS + (is_col ? 0 : NPBLK);
    float wl = 0.f;
    #pragma unroll
    for (int u = 0; u < 18; ++u)             // 18*64 = 1152
        wl = fmaxf(wl, wmx[lane + 64 * u]);
    #pragma unroll
    for (int off = 32; off > 0; off >>= 1)
        wl = fmaxf(wl, __shfl_xor(wl, off, 64));
    float Wmax = wl;
    int base = (b - (is_col ? CBASE : 0)) * RT;

    // wave wv builds rows 4wv..4wv+3 of A; exact shift M = Wmax*(amax-amin)
    #pragma unroll
    for (int q = 0; q < 4; ++q) {
        int rr = 4 * wv + q;
        int i, j; decomp((unsigned)(base + rr), i, j);
        float s = INV_TEMP * wself[i * NN + j];
        const float* Mi = Mat + i * NN;
        const float* Mj = Mat + j * NN;
        float v0 = s * (Mi[lane] - Mj[lane]);
        A[rr * NN + lane] = v0;
        float vmax = v0, vmin = v0;
        if (lane < 32) {
            float v1 = s * (Mi[64 + lane] - Mj[64 + lane]);
            A[rr * NN + 64 + lane] = v1;
            vmax = fmaxf(vmax, v1); vmin = fminf(vmin, v1);
        }
        #pragma unroll
        for (int off = 32; off > 0; off >>= 1) {
            vmax = fmaxf(vmax, __shfl_xor(vmax, off, 64));
            vmin = fminf(vmin, __shfl_xor(vmin, off, 64));
        }
        if (lane == 0) {
            float M = Wmax * (vmax - vmin);
            Ms[rr] = M;
            M2s[rr] = M * LOG2E;
        }
    }
    __syncthreads();

    int l1 = (lane < 32) ? (64 + lane) : (lane - 32);
    float M2[RT], aL0[RT], aL1[RT], aL2[RT], S[RT];
    #pragma unroll
    for (int r = 0; r < RT; ++r) {
        M2[r] = __int_as_float(__builtin_amdgcn_readfirstlane(__float_as_int(M2s[r])));
        aL0[r] = A[r * NN + lane];
        aL1[r] = A[r * NN + l1];
        aL2[r] = A[r * NN + lane + 32];
        S[r] = 0.f;
    }

    // wave wv handles idx = wv + 4u, u=0..11; k0 = 2*idx (wave-uniform).
    // ak read = LDS broadcast (wave-uniform addr, conflict-free).
    {
        int k0n = 2 * wv;
        float nw0 = wsweep[k0n * NN + lane];
        float nw1 = wsweep[(lane < 32 ? k0n : k0n + 1) * NN + l1];
        float nw2 = wsweep[(k0n + 1) * NN + lane + 32];
        #pragma unroll
        for (int u = 0; u < 12; ++u) {
            int k0 = 2 * (wv + 4 * u);
            float w0 = nw0, w1 = nw1, w2 = nw2;
            if (u < 11) {
                int nk0 = 2 * (wv + 4 * (u + 1));
                nw0 = wsweep[nk0 * NN + lane];
                nw1 = wsweep[(lane < 32 ? nk0 : nk0 + 1) * NN + l1];
                nw2 = wsweep[(nk0 + 1) * NN + lane + 32];
            }
            #pragma unroll
            for (int r = 0; r < RT; ++r) {
                float2 ak = *(const float2*)&A[r * NN + k0];   // k0 even -> 8B aligned
                float aksel = (lane < 32) ? ak.x : ak.y;
                S[r] += __builtin_amdgcn_exp2f(w0 * (ak.x  - aL0[r]) - M2[r])
                      + __builtin_amdgcn_exp2f(w1 * (aksel - aL1[r]) - M2[r])
                      + __builtin_amdgcn_exp2f(w2 * (ak.y  - aL2[r]) - M2[r]);
            }
        }
    }

    #pragma unroll
    for (int off = 32; off > 0; off >>= 1) {
        #pragma unroll
        for (int r = 0; r < RT; ++r) S[r] += __shfl_xor(S[r], off, 64);
    }
    if (lane == 0) {
        #pragma unroll
        for (int r = 0; r < RT; ++r) wred[wv][r] = S[r];
    }
    __syncthreads();

    if (tid < RT) {
        int r = tid;
        float tot = wred[0][r] + wred[1][r] + wred[2][r] + wred[3][r];
        tot -= 96.f * __builtin_amdgcn_exp2f(-M2s[r]);     // remove w=0 diagonal slots
        int i, j; decomp((unsigned)(base + r), i, j);
        float wtv = ws[OFF_WT + i * NN + j];
        float wmv = ws[OFF_WM + i * NN + j];
        float gii = ws[OFF_G + i * NN + i], gjj = ws[OFF_G + j * NN + j];
        float gij = ws[OFF_G + i * NN + j], gji = ws[OFF_G + j * NN + i];
        float dia = INV_TEMP * wtv * wmv * (gii - gij - gji + gjj);
        cred[r] = Ms[r] + logf(tot) - dia;
    }
    __syncthreads();
    if (tid == 0) {
        float c = 0.f;
        #pragma unroll
        for (int r = 0; r < RT; ++r) c += cred[r];
        wsw[OFF_BSUM + b] = c;      // contention-free partial; no atomics
    }
}

// K3: 1 block reduces 1140 partials -> out (deterministic).
__global__ __launch_bounds__(256) void final_kernel(const float* __restrict__ ws,
                                                    float* __restrict__ out) {
    __shared__ float red[256];
    int tid = threadIdx.x;
    float s = 0.f;
    for (int i = tid; i < NBLK_T; i += 256)
        s += ws[OFF_BSUM + i];
    red[tid] = s; __syncthreads();
    for (int t = 128; t > 0; t >>= 1) {
        if (tid < t) red[tid] += red[tid + t];
        __syncthreads();
    }
    if (tid == 0) out[0] = red[0] * (1.0f / (float)NTASK);
}

extern "C" void kernel_launch(void* const* d_in, const int* in_sizes, int n_in,
                              void* d_out, int out_size, void* d_ws, size_t ws_size,
                              hipStream_t stream) {
    const float* txt = (const float*)d_in[0];
    const float* img = (const float*)d_in[1];
    float* ws = (float*)d_ws;
    prep_kernel<<<NPBLK, 256, 0, stream>>>(txt, img, ws);
    lse_kernel<<<NBLK_T, 256, 0, stream>>>(ws, ws);
    final_kernel<<<1, 256, 0, stream>>>(ws, (float*)d_out);
}

// Round 10
// 102.259 us; speedup vs baseline: 2.8413x; 2.8413x over previous
//
#include <hip/hip_runtime.h>
#include <math.h>

#define NN 96
#define DD 512
#define PP 9120          // NN*(NN-1)
#define EPSF 1e-8f
#define INV_TEMP 100.0f
#define LOG2E 1.4426950408889634f
#define RT 8             // tasks per lse block (register-feasible width, cf. R9 spill)
#define NTASK (2*PP)     // 18240
#define NBLK_T (NTASK/RT) // 2280
#define CBASE (PP/RT)    // 1140: first block index handling column tasks
#define NPBLK 1152       // prep blocks (8 pairs each = 9216)

// ws float-offset layout (no init-dependent state: poison-proof)
#define OFF_G     0        // G  = txt*img^T   [96*96]
#define OFF_GT    9216     // GT = G^T
#define OFF_WT    18432    // wt[k][l] = 1/(||t_k-t_l||+eps), diag 0
#define OFF_WM    27648
#define OFF_WST   36864    // wt * log2e
#define OFF_WSM   46080    // wm * log2e
#define OFF_WMAXS 55296    // [0..1151] per-prep-block max wt, [1152..2303] max wm

__device__ __forceinline__ void decomp(unsigned p, int& i, int& j) {
    unsigned ii = p / 95u;
    unsigned r  = p - ii * 95u;
    i = (int)ii;
    j = (int)(r + (r >= ii ? 1u : 0u));
}

// K1: pair-per-wave prep (proven R4+). 1152 blocks x 4 waves x 2 pairs.
__global__ __launch_bounds__(256) void prep_kernel(const float* __restrict__ txt,
                                                   const float* __restrict__ img,
                                                   float* __restrict__ ws) {
    __shared__ float wtw[4], wmw[4];
    int b = blockIdx.x, tid = threadIdx.x;
    int lane = tid & 63, wv = tid >> 6;
    const float4* T4 = (const float4*)txt;   // row stride 128 float4
    const float4* M4 = (const float4*)img;
    float bwt = 0.f, bwm = 0.f;

    #pragma unroll
    for (int q = 0; q < 2; ++q) {
        int pp = b * 8 + wv * 2 + q;         // 0..9215
        int i = pp / NN, j = pp - i * NN;
        const float4* Ti = T4 + i * 128 + 2 * lane;
        const float4* Tj = T4 + j * 128 + 2 * lane;
        const float4* Mi = M4 + i * 128 + 2 * lane;
        const float4* Mj = M4 + j * 128 + 2 * lane;
        float gij = 0.f, nt2 = 0.f, nm2 = 0.f;
        #pragma unroll
        for (int u = 0; u < 2; ++u) {
            float4 a = Ti[u], t = Tj[u], c = Mi[u], d = Mj[u];
            gij += a.x*d.x + a.y*d.y + a.z*d.z + a.w*d.w;       // <t_i, m_j>
            float d0 = a.x-t.x, d1 = a.y-t.y, d2 = a.z-t.z, d3 = a.w-t.w;
            nt2 += d0*d0 + d1*d1 + d2*d2 + d3*d3;               // ||t_i-t_j||^2
            float e0 = c.x-d.x, e1 = c.y-d.y, e2 = c.z-d.z, e3 = c.w-d.w;
            nm2 += e0*e0 + e1*e1 + e2*e2 + e3*e3;               // ||m_i-m_j||^2
        }
        #pragma unroll
        for (int off = 32; off > 0; off >>= 1) {
            gij += __shfl_xor(gij, off, 64);
            nt2 += __shfl_xor(nt2, off, 64);
            nm2 += __shfl_xor(nm2, off, 64);
        }
        float wt = 0.f, wm = 0.f;
        if (i != j) {
            wt = 1.f / (sqrtf(fmaxf(nt2, 0.f)) + EPSF);
            wm = 1.f / (sqrtf(fmaxf(nm2, 0.f)) + EPSF);
        }
        bwt = fmaxf(bwt, wt); bwm = fmaxf(bwm, wm);
        if (lane == 0) {
            int t0 = i * NN + j;
            ws[OFF_G  + t0] = gij;
            ws[OFF_GT + j * NN + i] = gij;   // mirror pair fills GT[i*NN+j]
            ws[OFF_WT  + t0] = wt;
            ws[OFF_WM  + t0] = wm;
            ws[OFF_WST + t0] = wt * LOG2E;
            ws[OFF_WSM + t0] = wm * LOG2E;
        }
    }
    if (lane == 0) { wtw[wv] = bwt; wmw[wv] = bwm; }
    __syncthreads();
    if (tid == 0) {
        ws[OFF_WMAXS + b]         = fmaxf(fmaxf(wtw[0], wtw[1]), fmaxf(wtw[2], wtw[3]));
        ws[OFF_WMAXS + NPBLK + b] = fmaxf(fmaxf(wmw[0], wmw[1]), fmaxf(wmw[2], wmw[3]));
    }
}

// K2: lse with ALL 36 per-wave w-values hoisted to registers in the prologue
// (issued before the build phase -> latency hidden under build + barrier).
// Inner loop: zero VMEM — pure VALU + wave-uniform LDS broadcast of A[k].
__global__ __launch_bounds__(256, 2) void lse_kernel(const float* __restrict__ ws,
                                                     float* __restrict__ out) {
    __shared__ float A[RT * NN];
    __shared__ float M2s[RT];     // M * log2e
    __shared__ float Ms[RT];      // M
    __shared__ float wred[4][RT];
    __shared__ float cred[RT];

    int tid = threadIdx.x, lane = tid & 63, wv = tid >> 6;
    int b = blockIdx.x;
    bool is_col = (b >= CBASE);
    const float* Mat    = ws + (is_col ? OFF_GT  : OFF_G);
    const float* wself  = ws + (is_col ? OFF_WM  : OFF_WT);
    const float* wsweep = ws + (is_col ? OFF_WST : OFF_WSM);
    int l1 = (lane < 32) ? (64 + lane) : (lane - 32);

    // ---- deep prefetch: all 36 w-values for this wave's 12 sweep iterations ----
    float w0r[12], w1r[12], w2r[12];          // statically indexed (full unroll)
    #pragma unroll
    for (int u = 0; u < 12; ++u) {
        int k0 = 2 * (wv + 4 * u), k1 = k0 + 1;
        w0r[u] = wsweep[k0 * NN + lane];
        w1r[u] = wsweep[(lane < 32 ? k0 : k1) * NN + l1];
        w2r[u] = wsweep[k1 * NN + lane + 32];
    }

    // Wmax: rows sweep wm (partials at NPBLK..), cols sweep wt (partials at 0..)
    const float* wmx = ws + OFF_WMAXS + (is_col ? 0 : NPBLK);
    float wl = 0.f;
    #pragma unroll
    for (int u = 0; u < 18; ++u)             // 18*64 = 1152
        wl = fmaxf(wl, wmx[lane + 64 * u]);
    #pragma unroll
    for (int off = 32; off > 0; off >>= 1)
        wl = fmaxf(wl, __shfl_xor(wl, off, 64));
    float Wmax = wl;
    int base = (b - (is_col ? CBASE : 0)) * RT;

    // wave wv builds rows 2wv, 2wv+1 of A; exact shift M = Wmax*(amax-amin)
    #pragma unroll
    for (int q = 0; q < 2; ++q) {
        int rr = 2 * wv + q;
        int i, j; decomp((unsigned)(base + rr), i, j);
        float s = INV_TEMP * wself[i * NN + j];
        const float* Mi = Mat + i * NN;
        const float* Mj = Mat + j * NN;
        float v0 = s * (Mi[lane] - Mj[lane]);
        A[rr * NN + lane] = v0;
        float vmax = v0, vmin = v0;
        if (lane < 32) {
            float v1 = s * (Mi[64 + lane] - Mj[64 + lane]);
            A[rr * NN + 64 + lane] = v1;
            vmax = fmaxf(vmax, v1); vmin = fminf(vmin, v1);
        }
        #pragma unroll
        for (int off = 32; off > 0; off >>= 1) {
            vmax = fmaxf(vmax, __shfl_xor(vmax, off, 64));
            vmin = fminf(vmin, __shfl_xor(vmin, off, 64));
        }
        if (lane == 0) {
            float M = Wmax * (vmax - vmin);
            Ms[rr] = M;
            M2s[rr] = M * LOG2E;
        }
    }
    __syncthreads();

    float M2[RT], aL0[RT], aL1[RT], aL2[RT], S[RT];
    #pragma unroll
    for (int r = 0; r < RT; ++r) {
        M2[r] = __int_as_float(__builtin_amdgcn_readfirstlane(__float_as_int(M2s[r])));
        aL0[r] = A[r * NN + lane];
        aL1[r] = A[r * NN + l1];
        aL2[r] = A[r * NN + lane + 32];
        S[r] = 0.f;
    }

    // sweep: zero VMEM in loop; ak via wave-uniform LDS float2 broadcast
    #pragma unroll
    for (int u = 0; u < 12; ++u) {
        int k0 = 2 * (wv + 4 * u);
        float w0 = w0r[u], w1 = w1r[u], w2 = w2r[u];
        #pragma unroll
        for (int r = 0; r < RT; ++r) {
            float2 ak = *(const float2*)&A[r * NN + k0];   // k0 even -> 8B aligned
            float aksel = (lane < 32) ? ak.x : ak.y;
            S[r] += __builtin_amdgcn_exp2f(w0 * (ak.x  - aL0[r]) - M2[r])
                  + __builtin_amdgcn_exp2f(w1 * (aksel - aL1[r]) - M2[r])
                  + __builtin_amdgcn_exp2f(w2 * (ak.y  - aL2[r]) - M2[r]);
        }
    }

    #pragma unroll
    for (int off = 32; off > 0; off >>= 1) {
        #pragma unroll
        for (int r = 0; r < RT; ++r) S[r] += __shfl_xor(S[r], off, 64);
    }
    if (lane == 0) {
        #pragma unroll
        for (int r = 0; r < RT; ++r) wred[wv][r] = S[r];
    }
    __syncthreads();

    if (tid < RT) {
        int r = tid;
        float tot = wred[0][r] + wred[1][r] + wred[2][r] + wred[3][r];
        tot -= 96.f * __builtin_amdgcn_exp2f(-M2s[r]);     // remove w=0 diagonal slots
        int i, j; decomp((unsigned)(base + r), i, j);
        float wtv = ws[OFF_WT + i * NN + j];
        float wmv = ws[OFF_WM + i * NN + j];
        float gii = ws[OFF_G + i * NN + i], gjj = ws[OFF_G + j * NN + j];
        float gij = ws[OFF_G + i * NN + j], gji = ws[OFF_G + j * NN + i];
        float dia = INV_TEMP * wtv * wmv * (gii - gij - gji + gjj);
        cred[r] = Ms[r] + logf(tot) - dia;
    }
    __syncthreads();
    if (tid == 0) {
        float c = 0.f;
        #pragma unroll
        for (int r = 0; r < RT; ++r) c += cred[r];
        atomicAdd(out, c * (1.0f / (float)NTASK));   // out pre-zeroed by harness
    }
}

extern "C" void kernel_launch(void* const* d_in, const int* in_sizes, int n_in,
                              void* d_out, int out_size, void* d_ws, size_t ws_size,
                              hipStream_t stream) {
    const float* txt = (const float*)d_in[0];
    const float* img = (const float*)d_in[1];
    float* ws = (float*)d_ws;
    prep_kernel<<<NPBLK, 256, 0, stream>>>(txt, img, ws);
    lse_kernel<<<NBLK_T, 256, 0, stream>>>(ws, (float*)d_out);
}

// Round 11
// 99.033 us; speedup vs baseline: 2.9338x; 1.0326x over previous
//
#include <hip/hip_runtime.h>
#include <math.h>

#define NN 96
#define DD 512
#define PP 9120          // NN*(NN-1)
#define EPSF 1e-8f
#define INV_TEMP 100.0f
#define LOG2E 1.4426950408889634f
#define RT 8             // tasks per lse block
#define NTASK (2*PP)     // 18240
#define NBLK_T (NTASK/RT) // 2280
#define CBASE (PP/RT)    // 1140: first block index handling column tasks
#define NPBLK 1152       // prep blocks (8 pairs each = 9216)

// ws float-offset layout (no init-dependent state: poison-proof)
#define OFF_G     0        // G  = txt*img^T   [96*96]
#define OFF_GT    9216     // GT = G^T
#define OFF_WT    18432    // wt[k][l] = 1/(||t_k-t_l||+eps), diag 0
#define OFF_WM    27648
#define OFF_WST   36864    // wt * log2e
#define OFF_WSM   46080    // wm * log2e
#define OFF_WMAXS 55296    // [0..1151] per-prep-block max wt, [1152..2303] max wm

__device__ __forceinline__ void decomp(unsigned p, int& i, int& j) {
    unsigned ii = p / 95u;
    unsigned r  = p - ii * 95u;
    i = (int)ii;
    j = (int)(r + (r >= ii ? 1u : 0u));
}

// K1: pair-per-wave prep (proven R4+). 1152 blocks x 4 waves x 2 pairs.
__global__ __launch_bounds__(256) void prep_kernel(const float* __restrict__ txt,
                                                   const float* __restrict__ img,
                                                   float* __restrict__ ws) {
    __shared__ float wtw[4], wmw[4];
    int b = blockIdx.x, tid = threadIdx.x;
    int lane = tid & 63, wv = tid >> 6;
    const float4* T4 = (const float4*)txt;   // row stride 128 float4
    const float4* M4 = (const float4*)img;
    float bwt = 0.f, bwm = 0.f;

    #pragma unroll
    for (int q = 0; q < 2; ++q) {
        int pp = b * 8 + wv * 2 + q;         // 0..9215
        int i = pp / NN, j = pp - i * NN;
        const float4* Ti = T4 + i * 128 + 2 * lane;
        const float4* Tj = T4 + j * 128 + 2 * lane;
        const float4* Mi = M4 + i * 128 + 2 * lane;
        const float4* Mj = M4 + j * 128 + 2 * lane;
        float gij = 0.f, nt2 = 0.f, nm2 = 0.f;
        #pragma unroll
        for (int u = 0; u < 2; ++u) {
            float4 a = Ti[u], t = Tj[u], c = Mi[u], d = Mj[u];
            gij += a.x*d.x + a.y*d.y + a.z*d.z + a.w*d.w;       // <t_i, m_j>
            float d0 = a.x-t.x, d1 = a.y-t.y, d2 = a.z-t.z, d3 = a.w-t.w;
            nt2 += d0*d0 + d1*d1 + d2*d2 + d3*d3;               // ||t_i-t_j||^2
            float e0 = c.x-d.x, e1 = c.y-d.y, e2 = c.z-d.z, e3 = c.w-d.w;
            nm2 += e0*e0 + e1*e1 + e2*e2 + e3*e3;               // ||m_i-m_j||^2
        }
        #pragma unroll
        for (int off = 32; off > 0; off >>= 1) {
            gij += __shfl_xor(gij, off, 64);
            nt2 += __shfl_xor(nt2, off, 64);
            nm2 += __shfl_xor(nm2, off, 64);
        }
        float wt = 0.f, wm = 0.f;
        if (i != j) {
            wt = 1.f / (sqrtf(fmaxf(nt2, 0.f)) + EPSF);
            wm = 1.f / (sqrtf(fmaxf(nm2, 0.f)) + EPSF);
        }
        bwt = fmaxf(bwt, wt); bwm = fmaxf(bwm, wm);
        if (lane == 0) {
            int t0 = i * NN + j;
            ws[OFF_G  + t0] = gij;
            ws[OFF_GT + j * NN + i] = gij;   // mirror pair fills GT[i*NN+j]
            ws[OFF_WT  + t0] = wt;
            ws[OFF_WM  + t0] = wm;
            ws[OFF_WST + t0] = wt * LOG2E;
            ws[OFF_WSM + t0] = wm * LOG2E;
        }
    }
    if (lane == 0) { wtw[wv] = bwt; wmw[wv] = bwm; }
    __syncthreads();
    if (tid == 0) {
        ws[OFF_WMAXS + b]         = fmaxf(fmaxf(wtw[0], wtw[1]), fmaxf(wtw[2], wtw[3]));
        ws[OFF_WMAXS + NPBLK + b] = fmaxf(fmaxf(wmw[0], wmw[1]), fmaxf(wmw[2], wmw[3]));
    }
}

// K2: lse, 512 threads = 8 waves per block, RT=8. Per wave: build 1 row,
// sweep 6 u-iters (144 exp2), 18 w-loads prefetched to registers -> per-wave
// critical path HALVED vs the 4-wave variants. atomicAdd result (proven).
__global__ __launch_bounds__(512, 4) void lse_kernel(const float* __restrict__ ws,
                                                     float* __restrict__ out) {
    __shared__ float A[RT * NN];
    __shared__ float M2s[RT];     // M * log2e
    __shared__ float Ms[RT];      // M
    __shared__ float wred[8][RT];
    __shared__ float cred[RT];

    int tid = threadIdx.x, lane = tid & 63, wv = tid >> 6;   // wv 0..7
    int b = blockIdx.x;
    bool is_col = (b >= CBASE);
    const float* Mat    = ws + (is_col ? OFF_GT  : OFF_G);
    const float* wself  = ws + (is_col ? OFF_WM  : OFF_WT);
    const float* wsweep = ws + (is_col ? OFF_WST : OFF_WSM);
    int l1 = (lane < 32) ? (64 + lane) : (lane - 32);

    // deep prefetch: this wave's 18 w-values (6 iters x 3), static regs
    float w0r[6], w1r[6], w2r[6];
    #pragma unroll
    for (int t = 0; t < 6; ++t) {
        int k0 = 2 * (wv + 8 * t), k1 = k0 + 1;
        w0r[t] = wsweep[k0 * NN + lane];
        w1r[t] = wsweep[(lane < 32 ? k0 : k1) * NN + l1];
        w2r[t] = wsweep[k1 * NN + lane + 32];
    }

    // Wmax: rows sweep wm (partials at NPBLK..), cols sweep wt (partials at 0..)
    const float* wmx = ws + OFF_WMAXS + (is_col ? 0 : NPBLK);
    float wl = 0.f;
    #pragma unroll
    for (int u = 0; u < 18; ++u)             // 18*64 = 1152
        wl = fmaxf(wl, wmx[lane + 64 * u]);
    #pragma unroll
    for (int off = 32; off > 0; off >>= 1)
        wl = fmaxf(wl, __shfl_xor(wl, off, 64));
    float Wmax = wl;
    int base = (b - (is_col ? CBASE : 0)) * RT;

    // wave wv builds row wv of A; exact shift M = Wmax*(amax-amin)
    {
        int rr = wv;
        int i, j; decomp((unsigned)(base + rr), i, j);
        float s = INV_TEMP * wself[i * NN + j];
        const float* Mi = Mat + i * NN;
        const float* Mj = Mat + j * NN;
        float v0 = s * (Mi[lane] - Mj[lane]);
        A[rr * NN + lane] = v0;
        float vmax = v0, vmin = v0;
        if (lane < 32) {
            float v1 = s * (Mi[64 + lane] - Mj[64 + lane]);
            A[rr * NN + 64 + lane] = v1;
            vmax = fmaxf(vmax, v1); vmin = fminf(vmin, v1);
        }
        #pragma unroll
        for (int off = 32; off > 0; off >>= 1) {
            vmax = fmaxf(vmax, __shfl_xor(vmax, off, 64));
            vmin = fminf(vmin, __shfl_xor(vmin, off, 64));
        }
        if (lane == 0) {
            float M = Wmax * (vmax - vmin);
            Ms[rr] = M;
            M2s[rr] = M * LOG2E;
        }
    }
    __syncthreads();

    float M2[RT], aL0[RT], aL1[RT], aL2[RT], S[RT];
    #pragma unroll
    for (int r = 0; r < RT; ++r) {
        M2[r] = __int_as_float(__builtin_amdgcn_readfirstlane(__float_as_int(M2s[r])));
        aL0[r] = A[r * NN + lane];
        aL1[r] = A[r * NN + l1];
        aL2[r] = A[r * NN + lane + 32];
        S[r] = 0.f;
    }

    // sweep: wave wv handles idx = wv + 8t, t=0..5; zero VMEM in loop;
    // ak via wave-uniform LDS float2 broadcast (k0 even -> aligned).
    #pragma unroll
    for (int t = 0; t < 6; ++t) {
        int k0 = 2 * (wv + 8 * t);
        float w0 = w0r[t], w1 = w1r[t], w2 = w2r[t];
        #pragma unroll
        for (int r = 0; r < RT; ++r) {
            float2 ak = *(const float2*)&A[r * NN + k0];
            float aksel = (lane < 32) ? ak.x : ak.y;
            S[r] += __builtin_amdgcn_exp2f(w0 * (ak.x  - aL0[r]) - M2[r])
                  + __builtin_amdgcn_exp2f(w1 * (aksel - aL1[r]) - M2[r])
                  + __builtin_amdgcn_exp2f(w2 * (ak.y  - aL2[r]) - M2[r]);
        }
    }

    #pragma unroll
    for (int off = 32; off > 0; off >>= 1) {
        #pragma unroll
        for (int r = 0; r < RT; ++r) S[r] += __shfl_xor(S[r], off, 64);
    }
    if (lane == 0) {
        #pragma unroll
        for (int r = 0; r < RT; ++r) wred[wv][r] = S[r];
    }
    __syncthreads();

    if (tid < RT) {
        int r = tid;
        float tot = wred[0][r] + wred[1][r] + wred[2][r] + wred[3][r]
                  + wred[4][r] + wred[5][r] + wred[6][r] + wred[7][r];
        tot -= 96.f * __builtin_amdgcn_exp2f(-M2s[r]);     // remove w=0 diagonal slots
        int i, j; decomp((unsigned)(base + r), i, j);
        float wtv = ws[OFF_WT + i * NN + j];
        float wmv = ws[OFF_WM + i * NN + j];
        float gii = ws[OFF_G + i * NN + i], gjj = ws[OFF_G + j * NN + j];
        float gij = ws[OFF_G + i * NN + j], gji = ws[OFF_G + j * NN + i];
        float dia = INV_TEMP * wtv * wmv * (gii - gij - gji + gjj);
        cred[r] = Ms[r] + logf(tot) - dia;
    }
    __syncthreads();
    if (tid == 0) {
        float c = 0.f;
        #pragma unroll
        for (int r = 0; r < RT; ++r) c += cred[r];
        atomicAdd(out, c * (1.0f / (float)NTASK));   // out pre-zeroed by harness
    }
}

extern "C" void kernel_launch(void* const* d_in, const int* in_sizes, int n_in,
                              void* d_out, int out_size, void* d_ws, size_t ws_size,
                              hipStream_t stream) {
    const float* txt = (const float*)d_in[0];
    const float* img = (const float*)d_in[1];
    float* ws = (float*)d_ws;
    prep_kernel<<<NPBLK, 256, 0, stream>>>(txt, img, ws);
    lse_kernel<<<NBLK_T, 512, 0, stream>>>(ws, (float*)d_out);
}